// Round 7
// baseline (13031.058 us; speedup 1.0000x reference)
//
#include <hip/hip_runtime.h>
#include <math.h>

// Problem constants
#define BB   256    // batch
#define TT   1024   // timesteps
#define HH   512    // hidden
#define NWG  256    // 1 WG per CU
#define NTHR 512    // 8 waves
#define SLOT (HH*BB)   // elements per h slot; hi-plane u16 + lo-plane u8 (e5m2)
#define NSLOT 8     // h slot count (8 slots -> inv every 7th step)
#define PADX 20     // xch row stride (floats): conflict-free (verified: 10x conflict drop)

typedef _Float16 f16;
typedef _Float16 f16x8 __attribute__((ext_vector_type(8)));
typedef float    f32x4 __attribute__((ext_vector_type(4)));
typedef unsigned int u32;
typedef u32 u32x2 __attribute__((ext_vector_type(2)));
typedef u32 u32x4 __attribute__((ext_vector_type(4)));
typedef unsigned short u16;
typedef unsigned char u8;

__device__ __forceinline__ f32x4 mf(f16x8 a, f16x8 b, f32x4 c){
  return __builtin_amdgcn_mfma_f32_16x16x32_f16(a, b, c, 0, 0, 0);
}

__device__ __forceinline__ float fast_sigmoid(float v){
  float e = __expf(-v);
  return __builtin_amdgcn_rcpf(1.0f + e);
}
__device__ __forceinline__ float fast_tanh(float v){
  float a = fabsf(v);
  float e = __expf(-2.0f * a);
  float r = (1.0f - e) * __builtin_amdgcn_rcpf(1.0f + e);
  return copysignf(r, v);
}

// split h -> hi f16 bits + lo e5m2 byte (lo = (h-hi)*2048, RN via +0x80 before truncate;
// e5m2 == f16 with low 8 mantissa bits dropped, so e5m2->f16 is exactly <<8)
__device__ __forceinline__ void split_h(float hv, u16& hb, u8& lb){
  const f16 hh = (f16)hv;
  const f16 lh = (f16)((hv - (float)hh) * 2048.0f);
  union {f16 f; u16 u;} ch, cl; ch.f = hh; cl.f = lh;
  hb = ch.u;
  lb = (u8)(((u32)cl.u + 0x80u) >> 8);
}
__device__ __forceinline__ float join_h(u16 hb, u8 lb){
  union {u16 u; f16 f;} h, l;
  h.u = hb; l.u = (u16)((u32)lb << 8);
  return (float)h.f + (float)l.f * (1.0f/2048.0f);
}
// device-coherent write-through stores (land at L3/HBM; L2 never dirty for these)
__device__ __forceinline__ void st_wt_u16(u16* p, u16 v){
  __hip_atomic_store(p, v, __ATOMIC_RELAXED, __HIP_MEMORY_SCOPE_AGENT);
}
__device__ __forceinline__ void st_wt_u8(u8* p, u8 v){
  __hip_atomic_store(p, v, __ATOMIC_RELAXED, __HIP_MEMORY_SCOPE_AGENT);
}
__device__ __forceinline__ void st_wt_f32(float* p, float v){
  __hip_atomic_store(p, v, __ATOMIC_RELAXED, __HIP_MEMORY_SCOPE_AGENT);
}

// layout: h planes are [k>>3][b][k&7] so a lane's whole 8-k fragment is one
// contiguous 16B hi load + one 8B lo load. Expansion of the e5m2 lo bytes to
// f16 (<<8) via byte-perm, 2 bytes/dword.
__device__ __forceinline__ void build2(u32x4 hd, u32x2 ld2, f16x8& fh, f16x8& fl){
  union {u32 u[4]; f16x8 f;} H, L;
  H.u[0]=hd[0]; H.u[1]=hd[1]; H.u[2]=hd[2]; H.u[3]=hd[3];
  L.u[0] = __builtin_amdgcn_perm(ld2[0], 0u, 0x05010400u);  // k0,k1
  L.u[1] = __builtin_amdgcn_perm(ld2[0], 0u, 0x07010600u);  // k2,k3
  L.u[2] = __builtin_amdgcn_perm(ld2[1], 0u, 0x05010400u);  // k4,k5
  L.u[3] = __builtin_amdgcn_perm(ld2[1], 0u, 0x07010600u);  // k6,k7
  fh = H.f; fl = L.f;
}

// raw per-chunk load stage for ONE h matrix: hi 16B + lo 8B (6 VGPRs)
struct St1 { u32x4 h4; u32x2 l2; };

// GLOBAL fenced barrier (init only): all 256 WGs.
__device__ __forceinline__ void gridbar_g(unsigned* barb, unsigned ph){
  __syncthreads();
  if (threadIdx.x == 0){
    __builtin_amdgcn_fence(__ATOMIC_RELEASE, "agent");
    const unsigned g = blockIdx.x & 31u;
    unsigned old = __hip_atomic_fetch_add(&barb[g*16], 1u, __ATOMIC_RELAXED, __HIP_MEMORY_SCOPE_AGENT);
    if (old + 1u == 8u*ph){
      unsigned om = __hip_atomic_fetch_add(&barb[512], 1u, __ATOMIC_RELAXED, __HIP_MEMORY_SCOPE_AGENT);
      if (om + 1u == 32u*ph){
        #pragma unroll
        for (int r = 0; r < 32; ++r)
          __hip_atomic_store(&barb[544 + r*16], ph, __ATOMIC_RELAXED, __HIP_MEMORY_SCOPE_AGENT);
      }
    }
    while (__hip_atomic_load(&barb[544 + g*16], __ATOMIC_RELAXED, __HIP_MEMORY_SCOPE_AGENT) < ph){
      __builtin_amdgcn_s_sleep(2);
    }
    __builtin_amdgcn_fence(__ATOMIC_ACQUIRE, "agent");
  }
  __syncthreads();
}

// ws layout (bytes): [0,16K) barriers (dom0 @0, dom1 @4K, global @8K),
// [16K,16K+1M) xT fp32 [T][B], then h planes (EIGHT slots each):
// h1h u16[8*SLOT] (2MB), h1l u8[8*SLOT] (1MB), h2h u16[8*SLOT] (2MB),
// h2l u8[8*SLOT] (1MB)  -> 6.3MB h, ~7.4MB total.
//
// Domain counter block (1024 unsigneds per cb domain):
//   [g*16], g<16        : H2 arrival counters (fired at END of each phase)
//   [576 + g*16], g<16  : H1 arrival counters (fired MID-phase, after h1 store)
//
// R16 split-arrival pipeline: the layer-1 recurrence h1(t)->h1(t+1) is the
// only serial chain; layer-2/out have a full phase of slack. Each phase:
//   H1 half: gate H1>=8t -> load 16 h1 chunks -> 6 MFMA/chunk (L1 + L2's
//     h1-part) -> L1 cell -> store h1(t+1) -> syncthreads -> tid0 H1-arrival.
//   H2 half: gate H2>=8t -> load 16 h2 chunks -> 3 MFMA/chunk -> L2 cell ->
//     store h2(t) -> out reduce -> end barrier (H2 arrival, inv at t%7==6).
// Consumers' phase-(t+1) h1 gates open MID-phase-t (~2-3us early), so
// straggler/visibility wait on the critical chain overlaps the slack work.
// Soundness: H1-arrival implies that WG finished READING h1(t) (loads precede
// its own arrival in program order), so the 8-slot WAR window is unchanged;
// any phase-t gate implies all WGs passed their end-(t-2) barrier, which
// transitively contains the guaranteed inv at p<=tau+6 in every 8-read
// window (inv every 7th covers all residues in 7 consecutive phase-ends).
__global__ __launch_bounds__(NTHR, 2) void lstm_mfma(
    const float* __restrict__ x,      const float* __restrict__ W_ih1,
    const float* __restrict__ W_hh1,  const float* __restrict__ b1,
    const float* __restrict__ W_ih2,  const float* __restrict__ W_hh2,
    const float* __restrict__ b2,     const float* __restrict__ W_lin,
    const float* __restrict__ b_lin,  float* __restrict__ out,
    char* __restrict__ wsb)
{
  __shared__ f16x8 A2hi[2048], A2lo[2048], A1hi[1024], A1lo[1024]; // 96 KB
  __shared__ float xch[8][16*PADX];  // per-wave gate-exchange scratch (padded)
  __shared__ float wlin_s[512];
  __shared__ float outpart[2][8];

  unsigned* bar = (unsigned*)wsb;
  float* xT = (float*)(wsb + 16384);
  u16* h1h = (u16*)(wsb + 16384 + 1048576);
  u8*  h1l = (u8*) ((char*)h1h + 2*NSLOT*SLOT);   // after NSLOT slots of u16
  u16* h2h = (u16*)((char*)h1l + NSLOT*SLOT);     // after NSLOT slots of u8
  u8*  h2l = (u8*) ((char*)h2h + 2*NSLOT*SLOT);

  const int w   = blockIdx.x,  tid = threadIdx.x;
  const int l   = tid & 63,    wv  = tid >> 6;       // lane, wave
  const int quad = l >> 4,     lc  = l & 15;
  const int p = w >> 1, cb = w & 1;                  // row-group, batch half (cb == XCD parity)
  const int j0 = 4*p;                                // this WG's 4 hidden columns
  const int bcol = cb*128 + wv*16 + lc;              // this lane's batch column
  const int jq = j0 + quad;                          // this lane's j (post-exchange)
  const int b_out = cb*128 + p;                      // out row handled by this WG (intra-half)
  unsigned* dbar = bar + cb*1024;                    // domain barrier base
  unsigned* gbar = bar + 2048;                       // global barrier base
  const unsigned grp = (unsigned)(p >> 3);           // CONTIGUOUS arrival group == chunk index
  const int qrot = p & 3;                            // quarter rotation (spread L2 fills)
  // producer-side h element offset in [k>>3][b][k&7] layout (j = jq):
  const int hoff = (p>>1)*2048 + bcol*8 + (p&1)*4 + quad;

  // ---------------- init: weight split into LDS frag-order ----------------
  {
    const int g_ = lc >> 2, jj_ = lc & 3;            // A-row m = lc -> (gate, jj)
    const int wrow = g_*HH + j0 + jj_;
    const float* rowI  = W_ih2 + (size_t)wrow*HH;
    const float* rowH2 = W_hh2 + (size_t)wrow*HH;
    const float* rowH1 = W_hh1 + (size_t)wrow*HH;
    for (int c = wv; c < 32; c += 8){
      const int kb = c*32 + quad*8;
      union {f16x8 v; f16 e[8];} hi8, lo8;
      #pragma unroll
      for (int i = 0; i < 8; ++i){
        const int k = kb + i;
        const float wval = (k < HH) ? rowI[k] : rowH2[k - HH];
        const f16 h_ = (f16)wval;
        hi8.e[i] = h_;
        lo8.e[i] = (f16)((wval - (float)h_) * 2048.0f);
      }
      A2hi[c*64 + l] = hi8.v;
      A2lo[c*64 + l] = lo8.v;
    }
    for (int c = wv; c < 16; c += 8){
      const int kb = c*32 + quad*8;
      union {f16x8 v; f16 e[8];} hi8, lo8;
      #pragma unroll
      for (int i = 0; i < 8; ++i){
        const float wval = rowH1[kb + i];
        const f16 h_ = (f16)wval;
        hi8.e[i] = h_;
        lo8.e[i] = (f16)((wval - (float)h_) * 2048.0f);
      }
      A1hi[c*64 + l] = hi8.v;
      A1lo[c*64 + l] = lo8.v;
    }
  }
  // per-lane scalars (j = jq)
  float wih1r[4], b1r[4], b2r[4];
  #pragma unroll
  for (int g = 0; g < 4; ++g){
    wih1r[g] = W_ih1[g*HH + jq];
    b1r[g]   = b1[g*HH + jq];
    b2r[g]   = b2[g*HH + jq];
  }
  const float blin = b_lin[0];
  wlin_s[tid] = W_lin[tid];

  // x transpose -> xT[t][b] (plain stores; made visible by the fenced global barrier)
  {
    const int gid = w*NTHR + tid;
    #pragma unroll
    for (int i2 = 0; i2 < 2; ++i2){
      const int idx = gid + i2*131072;
      const int bb2 = idx >> 10, tt2 = idx & (TT-1);
      xT[(size_t)tt2*BB + bb2] = x[idx];
    }
  }
  // zero h2 slot NSLOT-1 (read as h2(-1) at t=0: slot (-1)&(NSLOT-1)) -- linear
  {
    const int idx = w*NTHR + tid;                     // [0, SLOT)
    st_wt_u16(&h2h[(NSLOT-1)*SLOT + idx], (u16)0);
    st_wt_u8 (&h2l[(NSLOT-1)*SLOT + idx], (u8)0);
  }

  gridbar_g(gbar, 1);

  // ---------------- prologue: h1(0), c-state init ----------------
  float c1, c2 = 0.0f;
  {
    const float xv0 = xT[bcol];
    const float gi = fast_sigmoid(fmaf(xv0, wih1r[0], b1r[0]));
    const float gg = fast_tanh   (fmaf(xv0, wih1r[2], b1r[2]));
    const float go = fast_sigmoid(fmaf(xv0, wih1r[3], b1r[3]));
    c1 = gi * gg;
    const float hv = go * fast_tanh(c1);
    u16 hb; u8 lb; split_h(hv, hb, lb);
    st_wt_u16(&h1h[hoff], hb);                        // h1(0) -> slot 0
    st_wt_u8 (&h1l[hoff], lb);
  }
  gridbar_g(gbar, 2);

  // combined readiness poll: lanes 0..15 read H2 group counters, lanes 16..31
  // read H1 counters; one ballot -> bits[0:16)=H2 ready, bits[16:32)=H1 ready.
  auto poll2 = [&](unsigned need) -> unsigned {
    const int li = l & 31;
    const unsigned off = (unsigned)((li & 15) * 16) + ((li & 16) ? 576u : 0u);
    unsigned cv = __hip_atomic_load(&dbar[off], __ATOMIC_RELAXED, __HIP_MEMORY_SCOPE_AGENT);
    return (unsigned)__ballot(cv >= need);
  };

  unsigned got = 0xFFFFFFFFu;   // phase 0: need=0, trivially ready

  // ---------------- main loop: phase t computes h1(t+1) [H1 half], then h2(t), out(t-1) [H2 half] ----------------
  for (int t = 0; t < TT; ++t){
    // slot of h-state tau is tau & (NSLOT-1)
    const int sR1 = ( t            & (NSLOT-1))*SLOT;   // h1(t)    (read)
    const int sR2 = ((t+NSLOT-1)   & (NSLOT-1))*SLOT;   // h2(t-1)  (read)
    const int sW1 = ((t+1)         & (NSLOT-1))*SLOT;   // h1(t+1)  (write)
    const int sW2 = ( t            & (NSLOT-1))*SLOT;   // h2(t)    (write)
    const unsigned need = 8u * (unsigned)t;

    f32x4 aA2 = {0,0,0,0}, aB2 = {0,0,0,0}, aA1 = {0,0,0,0}, aB1 = {0,0,0,0};
    const u16* q1h = h1h + sR1 + quad*2048 + bcol*8;
    const u8*  q1l = h1l + sR1 + quad*2048 + bcol*8;
    const u16* q2h = h2h + sR2 + quad*2048 + bcol*8;
    const u8*  q2l = h2l + sR2 + quad*2048 + bcol*8;

    auto waitq = [&](int qq, int base){              // base: 0 = H2 bits, 16 = H1 bits
      const unsigned qm = 0xFu << (base + 4*qq);
      while ((got & qm) != qm){
        __builtin_amdgcn_s_sleep(1);
        got |= poll2(need);
      }
      asm volatile("" ::: "memory");                 // gate: no data loads above the poll
    };
    auto ldc1 = [&](int c) -> St1 {
      St1 s; s.h4 = *(const u32x4*)(q1h + c*8192); s.l2 = *(const u32x2*)(q1l + c*8192); return s;
    };
    auto ldc2 = [&](int c) -> St1 {
      St1 s; s.h4 = *(const u32x4*)(q2h + c*8192); s.l2 = *(const u32x2*)(q2l + c*8192); return s;
    };
    auto cmp1 = [&](const St1& s, int c){            // h1 chunk: feeds L2's h1-part AND L1
      f16x8 bh, bl;
      build2(s.h4, s.l2, bh, bl);
      const f16x8 a2h = A2hi[c*64 + l];
      const f16x8 a2l = A2lo[c*64 + l];
      const f16x8 a1h = A1hi[c*64 + l];
      const f16x8 a1l = A1lo[c*64 + l];
      aA2 = mf(a2h, bh, aA2);
      aB2 = mf(a2h, bl, aB2);
      aB2 = mf(a2l, bh, aB2);
      aA1 = mf(a1h, bh, aA1);
      aB1 = mf(a1h, bl, aB1);
      aB1 = mf(a1l, bh, aB1);
    };
    auto cmp2 = [&](const St1& s, int c){            // h2 chunk: L2's h2-part only
      f16x8 ch, cl2;
      build2(s.h4, s.l2, ch, cl2);
      const f16x8 d2h = A2hi[(c+16)*64 + l];
      const f16x8 d2l = A2lo[(c+16)*64 + l];
      aA2 = mf(d2h, ch, aA2);
      aB2 = mf(d2h, cl2, aB2);
      aB2 = mf(d2l, ch, aB2);
    };

    const int cq0 = 4*qrot;
    const int cq1 = 4*((qrot+1)&3);
    const int cq2 = 4*((qrot+2)&3);
    const int cq3 = 4*((qrot+3)&3);

    // ======== H1 half: 16 h1 chunks, quarter-pipelined, gated on H1 bits ========
    {
      St1 SA0,SA1,SA2,SA3, SB0,SB1,SB2,SB3;
      waitq(cq0 >> 2, 16);
      SA0=ldc1(cq0+0); SA1=ldc1(cq0+1); SA2=ldc1(cq0+2); SA3=ldc1(cq0+3);
      waitq(cq1 >> 2, 16);
      SB0=ldc1(cq1+0); SB1=ldc1(cq1+1); SB2=ldc1(cq1+2); SB3=ldc1(cq1+3);
      cmp1(SA0,cq0+0); cmp1(SA1,cq0+1); cmp1(SA2,cq0+2); cmp1(SA3,cq0+3);
      waitq(cq2 >> 2, 16);
      SA0=ldc1(cq2+0); SA1=ldc1(cq2+1); SA2=ldc1(cq2+2); SA3=ldc1(cq2+3);
      cmp1(SB0,cq1+0); cmp1(SB1,cq1+1); cmp1(SB2,cq1+2); cmp1(SB3,cq1+3);
      waitq(cq3 >> 2, 16);
      SB0=ldc1(cq3+0); SB1=ldc1(cq3+1); SB2=ldc1(cq3+2); SB3=ldc1(cq3+3);
      cmp1(SA0,cq2+0); cmp1(SA1,cq2+1); cmp1(SA2,cq2+2); cmp1(SA3,cq2+3);
      cmp1(SB0,cq3+0); cmp1(SB1,cq3+1); cmp1(SB2,cq3+2); cmp1(SB3,cq3+3);
    }

    float* xw = &xch[wv][0];
    // ---- layer-1 cell (for t+1): runs FIRST so h1(t+1) releases mid-phase ----
    {
      f32x4 pre;
      #pragma unroll
      for (int i = 0; i < 4; ++i) pre[i] = fmaf(aB1[i], 1.0f/2048.0f, aA1[i]);
      __threadfence_block();                          // prior phase's reads done before overwrite
      *(f32x4*)&xw[lc*PADX + quad*4] = pre;          // [col][row], padded
      __threadfence_block();
      const float g0 = xw[lc*PADX + 0*4 + quad];
      const float g1 = xw[lc*PADX + 1*4 + quad];
      const float g2 = xw[lc*PADX + 2*4 + quad];
      const float g3 = xw[lc*PADX + 3*4 + quad];
      const int tx = (t+1 < TT) ? (t+1) : (TT-1);
      const float xv = xT[(size_t)tx*BB + bcol];
      const float gi = fast_sigmoid(g0 + fmaf(xv, wih1r[0], b1r[0]));
      const float gf = fast_sigmoid(g1 + fmaf(xv, wih1r[1], b1r[1]));
      const float gg = fast_tanh   (g2 + fmaf(xv, wih1r[2], b1r[2]));
      const float go = fast_sigmoid(g3 + fmaf(xv, wih1r[3], b1r[3]));
      c1 = fmaf(gf, c1, gi*gg);
      const float hv = go * fast_tanh(c1);
      u16 hb; u8 lb; split_h(hv, hb, lb);
      st_wt_u16(&h1h[sW1 + hoff], hb);
      st_wt_u8 (&h1l[sW1 + hoff], lb);
    }
    // ---- MID-phase H1 arrival: h1(t+1) released ~2-3us before the end barrier ----
    __syncthreads();                                   // drains all waves' h1 WT stores
    if (tid == 0){
      __builtin_amdgcn_fence(__ATOMIC_RELEASE, "workgroup");
      __hip_atomic_fetch_add(&dbar[576 + grp*16], 1u, __ATOMIC_RELAXED, __HIP_MEMORY_SCOPE_AGENT);
    }

    // ======== H2 half: 16 h2 chunks, quarter-pipelined, gated on H2 bits ========
    u16 ohb; u8 olb;
    {
      St1 SA0,SA1,SA2,SA3, SB0,SB1,SB2,SB3;
      waitq(cq0 >> 2, 0);
      SA0=ldc2(cq0+0); SA1=ldc2(cq0+1); SA2=ldc2(cq0+2); SA3=ldc2(cq0+3);
      waitq(cq1 >> 2, 0);
      SB0=ldc2(cq1+0); SB1=ldc2(cq1+1); SB2=ldc2(cq1+2); SB3=ldc2(cq1+3);
      cmp2(SA0,cq0+0); cmp2(SA1,cq0+1); cmp2(SA2,cq0+2); cmp2(SA3,cq0+3);
      waitq(cq2 >> 2, 0);
      SA0=ldc2(cq2+0); SA1=ldc2(cq2+1); SA2=ldc2(cq2+2); SA3=ldc2(cq2+3);
      cmp2(SB0,cq1+0); cmp2(SB1,cq1+1); cmp2(SB2,cq1+2); cmp2(SB3,cq1+3);
      waitq(cq3 >> 2, 0);
      SB0=ldc2(cq3+0); SB1=ldc2(cq3+1); SB2=ldc2(cq3+2); SB3=ldc2(cq3+3);
      // out(t-1) read: ALL 16 H2 gates passed (4 quarters above) -> h2(t-1)
      // fully released; hides under the final 8 cmp chunks.
      const int oidx = sR2 + (tid>>3)*2048 + b_out*8 + (tid&7);
      ohb = h2h[oidx];
      olb = h2l[oidx];
      cmp2(SA0,cq2+0); cmp2(SA1,cq2+1); cmp2(SA2,cq2+2); cmp2(SA3,cq2+3);
      cmp2(SB0,cq3+0); cmp2(SB1,cq3+1); cmp2(SB2,cq3+2); cmp2(SB3,cq3+3);
    }

    float opart = join_h(ohb, olb) * wlin_s[tid];

    // ---- layer-2 cell (lane -> jj=quad, b=bcol after exchange) ----
    {
      f32x4 pre;
      #pragma unroll
      for (int i = 0; i < 4; ++i) pre[i] = fmaf(aB2[i], 1.0f/2048.0f, aA2[i]);
      __threadfence_block();                          // L1 cell's reads done before overwrite
      *(f32x4*)&xw[lc*PADX + quad*4] = pre;
      __threadfence_block();
      const float g0 = xw[lc*PADX + 0*4 + quad];
      const float g1 = xw[lc*PADX + 1*4 + quad];
      const float g2 = xw[lc*PADX + 2*4 + quad];
      const float g3 = xw[lc*PADX + 3*4 + quad];
      const float gi = fast_sigmoid(g0 + b2r[0]);
      const float gf = fast_sigmoid(g1 + b2r[1]);
      const float gg = fast_tanh   (g2 + b2r[2]);
      const float go = fast_sigmoid(g3 + b2r[3]);
      c2 = fmaf(gf, c2, gi*gg);
      const float hv = go * fast_tanh(c2);
      u16 hb; u8 lb; split_h(hv, hb, lb);
      st_wt_u16(&h2h[sW2 + hoff], hb);
      st_wt_u8 (&h2l[sW2 + hoff], lb);
    }
    // ---- out(t-1) reduce (lands pre-syncthreads) ----
    #pragma unroll
    for (int off = 32; off > 0; off >>= 1) opart += __shfl_down(opart, off, 64);
    if (l == 0) outpart[t & 1][wv] = opart;

    // ---- end barrier: H2 arrival; L2-inv only at t%7==6 (8-slot window) ----
    __syncthreads();                                   // drains WT stores (vmcnt 0)
    if (tid == 0){
      __builtin_amdgcn_fence(__ATOMIC_RELEASE, "workgroup");   // ordering only, no wbl2
      __hip_atomic_fetch_add(&dbar[grp*16], 1u, __ATOMIC_RELAXED, __HIP_MEMORY_SCOPE_AGENT);
      if (t % 7 == 6){
        __builtin_amdgcn_fence(__ATOMIC_ACQUIRE, "agent");  // EARLY buffer_inv, off critical path
      }
      if (t > 0){                                     // overlap with other WGs' arrivals
        float s = blin;
        #pragma unroll
        for (int q2i = 0; q2i < 8; ++q2i) s += outpart[t & 1][q2i];
        st_wt_f32(&out[(size_t)b_out*TT + (t-1)], s);
      }
    }
    got = poll2(8u * (unsigned)(t+1));                 // pre-poll next phase (overlaps tail)
    __syncthreads();                                   // inv complete before any wave's next loads
  }

  // ---------------- tail: out(1023) (needs all phase-1023 H2 arrivals) ----------------
  {
    const unsigned needT = 8u * (unsigned)TT;
    while ((got & 0xFFFFu) != 0xFFFFu){
      __builtin_amdgcn_s_sleep(1);
      got |= poll2(needT);
    }
    asm volatile("" ::: "memory");

    const int oidx = ((TT-1)&(NSLOT-1))*SLOT + (tid>>3)*2048 + b_out*8 + (tid&7);
    float opart = join_h(h2h[oidx], h2l[oidx]) * wlin_s[tid];
    #pragma unroll
    for (int off = 32; off > 0; off >>= 1) opart += __shfl_down(opart, off, 64);
    if (l == 0) outpart[0][wv] = opart;
    __syncthreads();
    if (tid == 0){
      float s = blin;
      #pragma unroll
      for (int q2i = 0; q2i < 8; ++q2i) s += outpart[0][q2i];
      st_wt_f32(&out[(size_t)b_out*TT + (TT-1)], s);
    }
  }
}

extern "C" void kernel_launch(void* const* d_in, const int* in_sizes, int n_in,
                              void* d_out, int out_size, void* d_ws, size_t ws_size,
                              hipStream_t stream) {
  const float* x     = (const float*)d_in[0];
  const float* W_ih1 = (const float*)d_in[1];
  const float* W_hh1 = (const float*)d_in[2];
  const float* b1    = (const float*)d_in[3];
  const float* W_ih2 = (const float*)d_in[4];
  const float* W_hh2 = (const float*)d_in[5];
  const float* b2    = (const float*)d_in[6];
  const float* W_lin = (const float*)d_in[7];
  const float* b_lin = (const float*)d_in[8];
  float* out = (float*)d_out;
  char* wsb  = (char*)d_ws;

  // zero the barrier region (ws is re-poisoned to 0xAA before every launch)
  hipMemsetAsync(d_ws, 0, 16384, stream);

  hipLaunchKernelGGL(lstm_mfma, dim3(NWG), dim3(NTHR), 0, stream,
                     x, W_ih1, W_hh1, b1, W_ih2, W_hh2, b2, W_lin, b_lin, out, wsb);
}

// Round 8
// 10312.174 us; speedup vs baseline: 1.2637x; 1.2637x over previous
//
#include <hip/hip_runtime.h>
#include <math.h>

// Problem constants
#define BB   256    // batch
#define TT   1024   // timesteps
#define HH   512    // hidden
#define NWG  256    // 1 WG per CU
#define NTHR 512    // 8 waves
#define SLOT (HH*BB)   // elements per h slot; hi-plane u16 + lo-plane u8 (e5m2)
#define NSLOT 8     // h slot count (8 slots -> inv every 7th step)
#define PADX 20     // xch row stride (floats): conflict-free (verified: 10x conflict drop)

typedef _Float16 f16;
typedef _Float16 f16x8 __attribute__((ext_vector_type(8)));
typedef float    f32x4 __attribute__((ext_vector_type(4)));
typedef unsigned int u32;
typedef u32 u32x2 __attribute__((ext_vector_type(2)));
typedef u32 u32x4 __attribute__((ext_vector_type(4)));
typedef unsigned short u16;
typedef unsigned char u8;

__device__ __forceinline__ f32x4 mf(f16x8 a, f16x8 b, f32x4 c){
  return __builtin_amdgcn_mfma_f32_16x16x32_f16(a, b, c, 0, 0, 0);
}

__device__ __forceinline__ float fast_sigmoid(float v){
  float e = __expf(-v);
  return __builtin_amdgcn_rcpf(1.0f + e);
}
__device__ __forceinline__ float fast_tanh(float v){
  float a = fabsf(v);
  float e = __expf(-2.0f * a);
  float r = (1.0f - e) * __builtin_amdgcn_rcpf(1.0f + e);
  return copysignf(r, v);
}

// split h -> hi f16 bits + lo e5m2 byte (lo = (h-hi)*2048, RN via +0x80 before truncate;
// e5m2 == f16 with low 8 mantissa bits dropped, so e5m2->f16 is exactly <<8)
__device__ __forceinline__ void split_h(float hv, u16& hb, u8& lb){
  const f16 hh = (f16)hv;
  const f16 lh = (f16)((hv - (float)hh) * 2048.0f);
  union {f16 f; u16 u;} ch, cl; ch.f = hh; cl.f = lh;
  hb = ch.u;
  lb = (u8)(((u32)cl.u + 0x80u) >> 8);
}
__device__ __forceinline__ float join_h(u16 hb, u8 lb){
  union {u16 u; f16 f;} h, l;
  h.u = hb; l.u = (u16)((u32)lb << 8);
  return (float)h.f + (float)l.f * (1.0f/2048.0f);
}
// device-coherent write-through stores (land at L3/HBM; L2 never dirty for these)
__device__ __forceinline__ void st_wt_u16(u16* p, u16 v){
  __hip_atomic_store(p, v, __ATOMIC_RELAXED, __HIP_MEMORY_SCOPE_AGENT);
}
__device__ __forceinline__ void st_wt_u8(u8* p, u8 v){
  __hip_atomic_store(p, v, __ATOMIC_RELAXED, __HIP_MEMORY_SCOPE_AGENT);
}
__device__ __forceinline__ void st_wt_f32(float* p, float v){
  __hip_atomic_store(p, v, __ATOMIC_RELAXED, __HIP_MEMORY_SCOPE_AGENT);
}

// layout: h planes are [k>>3][b][k&7] so a lane's whole 8-k fragment is one
// contiguous 16B hi load + one 8B lo load. Expansion of the e5m2 lo bytes to
// f16 (<<8) via byte-perm, 2 bytes/dword.
__device__ __forceinline__ void build2(u32x4 hd, u32x2 ld2, f16x8& fh, f16x8& fl){
  union {u32 u[4]; f16x8 f;} H, L;
  H.u[0]=hd[0]; H.u[1]=hd[1]; H.u[2]=hd[2]; H.u[3]=hd[3];
  L.u[0] = __builtin_amdgcn_perm(ld2[0], 0u, 0x05010400u);  // k0,k1
  L.u[1] = __builtin_amdgcn_perm(ld2[0], 0u, 0x07010600u);  // k2,k3
  L.u[2] = __builtin_amdgcn_perm(ld2[1], 0u, 0x05010400u);  // k4,k5
  L.u[3] = __builtin_amdgcn_perm(ld2[1], 0u, 0x07010600u);  // k6,k7
  fh = H.f; fl = L.f;
}

// raw per-chunk load stage: h1 hi 16B + h1 lo 8B + h2 hi 16B + h2 lo 8B (12 VGPRs)
struct St { u32x4 h1h4; u32x2 h1l2; u32x4 h2h4; u32x2 h2l2; };

// GLOBAL fenced barrier (init only): all 256 WGs.
__device__ __forceinline__ void gridbar_g(unsigned* barb, unsigned ph){
  __syncthreads();
  if (threadIdx.x == 0){
    __builtin_amdgcn_fence(__ATOMIC_RELEASE, "agent");
    const unsigned g = blockIdx.x & 31u;
    unsigned old = __hip_atomic_fetch_add(&barb[g*16], 1u, __ATOMIC_RELAXED, __HIP_MEMORY_SCOPE_AGENT);
    if (old + 1u == 8u*ph){
      unsigned om = __hip_atomic_fetch_add(&barb[512], 1u, __ATOMIC_RELAXED, __HIP_MEMORY_SCOPE_AGENT);
      if (om + 1u == 32u*ph){
        #pragma unroll
        for (int r = 0; r < 32; ++r)
          __hip_atomic_store(&barb[544 + r*16], ph, __ATOMIC_RELAXED, __HIP_MEMORY_SCOPE_AGENT);
      }
    }
    while (__hip_atomic_load(&barb[544 + g*16], __ATOMIC_RELAXED, __HIP_MEMORY_SCOPE_AGENT) < ph){
      __builtin_amdgcn_s_sleep(2);
    }
    __builtin_amdgcn_fence(__ATOMIC_ACQUIRE, "agent");
  }
  __syncthreads();
}

// ws layout (bytes): [0,16K) barriers (dom0 @0, dom1 @4K, global @8K),
// [16K,16K+1M) xT fp32 [T][B], then h planes (EIGHT slots each):
// h1h u16[8*SLOT] (2MB), h1l u8[8*SLOT] (1MB), h2h u16[8*SLOT] (2MB),
// h2l u8[8*SLOT] (1MB)  -> 6.3MB h, ~7.4MB total.
//
// Barrier protocol (R10): arrival groups contiguous in p (grp=p>>3) so group
// g == K-chunk c=g. No master/release; waves self-release by polling the 16
// group counters (16-lane load + ballot). Gate-before-load; writes only after
// all 16 gates => WAR-safe. 8 slots + inv at t%7==6 (R15): slot lines re-enter
// L2 only via post-gate reads (every 8 steps); any 7 consecutive steps contain
// one inv, so the stale window always straddles an inv.
//
// R17: the per-step tail is taken OFF the critical path.
//  (a) The SECOND per-step __syncthreads is removed: post-gate loads are
//      always fresh (gate => producer's WT store reached L3, and the
//      consumer's L2 line is invalid-by-window), so the inv may overlap
//      other waves' next-phase loads -- it can only kill a FRESH fill
//      (harmless refetch), never expose a stale one. Run-ahead is bounded
//      to <=1 phase: t+2 gates need this WG's own t+1 arrival, which needs
//      tid0 through t+1's drain barrier.
//  (b) tid0's serial tail is split: tid0 does fence+arrival(+inv); tid64
//      (wave-1 lane0) concurrently does the out-reduce + out store.
__global__ __launch_bounds__(NTHR, 2) void lstm_mfma(
    const float* __restrict__ x,      const float* __restrict__ W_ih1,
    const float* __restrict__ W_hh1,  const float* __restrict__ b1,
    const float* __restrict__ W_ih2,  const float* __restrict__ W_hh2,
    const float* __restrict__ b2,     const float* __restrict__ W_lin,
    const float* __restrict__ b_lin,  float* __restrict__ out,
    char* __restrict__ wsb)
{
  __shared__ f16x8 A2hi[2048], A2lo[2048], A1hi[1024], A1lo[1024]; // 96 KB
  __shared__ float xch[8][16*PADX];  // per-wave gate-exchange scratch (padded)
  __shared__ float wlin_s[512];
  __shared__ float outpart[2][8];

  unsigned* bar = (unsigned*)wsb;
  float* xT = (float*)(wsb + 16384);
  u16* h1h = (u16*)(wsb + 16384 + 1048576);
  u8*  h1l = (u8*) ((char*)h1h + 2*NSLOT*SLOT);   // after NSLOT slots of u16
  u16* h2h = (u16*)((char*)h1l + NSLOT*SLOT);     // after NSLOT slots of u8
  u8*  h2l = (u8*) ((char*)h2h + 2*NSLOT*SLOT);

  const int w   = blockIdx.x,  tid = threadIdx.x;
  const int l   = tid & 63,    wv  = tid >> 6;       // lane, wave
  const int quad = l >> 4,     lc  = l & 15;
  const int p = w >> 1, cb = w & 1;                  // row-group, batch half (cb == XCD parity)
  const int j0 = 4*p;                                // this WG's 4 hidden columns
  const int bcol = cb*128 + wv*16 + lc;              // this lane's batch column
  const int jq = j0 + quad;                          // this lane's j (post-exchange)
  const int b_out = cb*128 + p;                      // out row handled by this WG (intra-half)
  unsigned* dbar = bar + cb*1024;                    // domain barrier base
  unsigned* gbar = bar + 2048;                       // global barrier base
  const unsigned grp = (unsigned)(p >> 3);           // CONTIGUOUS arrival group == chunk index
  const int qrot = p & 3;                            // quarter rotation (spread L2 fills)
  // producer-side h element offset in [k>>3][b][k&7] layout (j = jq):
  const int hoff = (p>>1)*2048 + bcol*8 + (p&1)*4 + quad;

  // ---------------- init: weight split into LDS frag-order ----------------
  {
    const int g_ = lc >> 2, jj_ = lc & 3;            // A-row m = lc -> (gate, jj)
    const int wrow = g_*HH + j0 + jj_;
    const float* rowI  = W_ih2 + (size_t)wrow*HH;
    const float* rowH2 = W_hh2 + (size_t)wrow*HH;
    const float* rowH1 = W_hh1 + (size_t)wrow*HH;
    for (int c = wv; c < 32; c += 8){
      const int kb = c*32 + quad*8;
      union {f16x8 v; f16 e[8];} hi8, lo8;
      #pragma unroll
      for (int i = 0; i < 8; ++i){
        const int k = kb + i;
        const float wval = (k < HH) ? rowI[k] : rowH2[k - HH];
        const f16 h_ = (f16)wval;
        hi8.e[i] = h_;
        lo8.e[i] = (f16)((wval - (float)h_) * 2048.0f);
      }
      A2hi[c*64 + l] = hi8.v;
      A2lo[c*64 + l] = lo8.v;
    }
    for (int c = wv; c < 16; c += 8){
      const int kb = c*32 + quad*8;
      union {f16x8 v; f16 e[8];} hi8, lo8;
      #pragma unroll
      for (int i = 0; i < 8; ++i){
        const float wval = rowH1[kb + i];
        const f16 h_ = (f16)wval;
        hi8.e[i] = h_;
        lo8.e[i] = (f16)((wval - (float)h_) * 2048.0f);
      }
      A1hi[c*64 + l] = hi8.v;
      A1lo[c*64 + l] = lo8.v;
    }
  }
  // per-lane scalars (j = jq)
  float wih1r[4], b1r[4], b2r[4];
  #pragma unroll
  for (int g = 0; g < 4; ++g){
    wih1r[g] = W_ih1[g*HH + jq];
    b1r[g]   = b1[g*HH + jq];
    b2r[g]   = b2[g*HH + jq];
  }
  const float blin = b_lin[0];
  wlin_s[tid] = W_lin[tid];

  // x transpose -> xT[t][b] (plain stores; made visible by the fenced global barrier)
  {
    const int gid = w*NTHR + tid;
    #pragma unroll
    for (int i2 = 0; i2 < 2; ++i2){
      const int idx = gid + i2*131072;
      const int bb2 = idx >> 10, tt2 = idx & (TT-1);
      xT[(size_t)tt2*BB + bb2] = x[idx];
    }
  }
  // zero h2 slot NSLOT-1 (read as h2(-1) at t=0: slot (-1)&(NSLOT-1)) -- linear
  {
    const int idx = w*NTHR + tid;                     // [0, SLOT)
    st_wt_u16(&h2h[(NSLOT-1)*SLOT + idx], (u16)0);
    st_wt_u8 (&h2l[(NSLOT-1)*SLOT + idx], (u8)0);
  }

  gridbar_g(gbar, 1);

  // ---------------- prologue: h1(0), c-state init ----------------
  float c1, c2 = 0.0f;
  {
    const float xv0 = xT[bcol];
    const float gi = fast_sigmoid(fmaf(xv0, wih1r[0], b1r[0]));
    const float gg = fast_tanh   (fmaf(xv0, wih1r[2], b1r[2]));
    const float go = fast_sigmoid(fmaf(xv0, wih1r[3], b1r[3]));
    c1 = gi * gg;
    const float hv = go * fast_tanh(c1);
    u16 hb; u8 lb; split_h(hv, hb, lb);
    st_wt_u16(&h1h[hoff], hb);                        // h1(0) -> slot 0
    st_wt_u8 (&h1l[hoff], lb);
  }
  gridbar_g(gbar, 2);

  // readiness poll: lanes 0..15 read the 16 group counters, ballot -> mask
  auto poll_mask = [&](unsigned need) -> unsigned {
    unsigned cv = __hip_atomic_load(&dbar[(l & 15) * 16], __ATOMIC_RELAXED, __HIP_MEMORY_SCOPE_AGENT);
    return (unsigned)__ballot(cv >= need) & 0xFFFFu;
  };

  unsigned got = 0xFFFFu;   // phase 0: need=0, trivially ready

  // ---------------- main loop: phase t computes h2(t), h1(t+1), out(t-1) ----------------
  for (int t = 0; t < TT; ++t){
    // slot of h-state tau is tau & (NSLOT-1)
    const int sR1 = ( t            & (NSLOT-1))*SLOT;   // h1(t)    (read)
    const int sR2 = ((t+NSLOT-1)   & (NSLOT-1))*SLOT;   // h2(t-1)  (read)
    const int sW1 = ((t+1)         & (NSLOT-1))*SLOT;   // h1(t+1)  (write)
    const int sW2 = ( t            & (NSLOT-1))*SLOT;   // h2(t)    (write)
    const unsigned need = 8u * (unsigned)t;

    f32x4 aA2 = {0,0,0,0}, aB2 = {0,0,0,0}, aA1 = {0,0,0,0}, aB1 = {0,0,0,0};
    const u16* q1h = h1h + sR1 + quad*2048 + bcol*8;
    const u8*  q1l = h1l + sR1 + quad*2048 + bcol*8;
    const u16* q2h = h2h + sR2 + quad*2048 + bcol*8;
    const u8*  q2l = h2l + sR2 + quad*2048 + bcol*8;

    auto waitq = [&](int qq){
      const unsigned qm = 0xFu << (4*qq);
      while ((got & qm) != qm){
        __builtin_amdgcn_s_sleep(1);
        got |= poll_mask(need);
      }
      asm volatile("" ::: "memory");                 // gate: no data loads above the poll
    };
    auto ldc = [&](int c) -> St {
      St s;
      s.h1h4 = *(const u32x4*)(q1h + c*8192);
      s.h1l2 = *(const u32x2*)(q1l + c*8192);
      s.h2h4 = *(const u32x4*)(q2h + c*8192);
      s.h2l2 = *(const u32x2*)(q2l + c*8192);
      return s;
    };
    auto cmp = [&](const St& s, int c){
      f16x8 bh, bl;
      build2(s.h1h4, s.h1l2, bh, bl);
      const f16x8 a2h = A2hi[c*64 + l];
      const f16x8 a2l = A2lo[c*64 + l];
      const f16x8 a1h = A1hi[c*64 + l];
      const f16x8 a1l = A1lo[c*64 + l];
      aA2 = mf(a2h, bh, aA2);
      aB2 = mf(a2h, bl, aB2);
      aB2 = mf(a2l, bh, aB2);
      aA1 = mf(a1h, bh, aA1);
      aB1 = mf(a1h, bl, aB1);
      aB1 = mf(a1l, bh, aB1);
      f16x8 ch, cl2;
      build2(s.h2h4, s.h2l2, ch, cl2);
      const f16x8 d2h = A2hi[(c+16)*64 + l];
      const f16x8 d2l = A2lo[(c+16)*64 + l];
      aA2 = mf(d2h, ch, aA2);
      aB2 = mf(d2h, cl2, aB2);
      aB2 = mf(d2l, ch, aB2);
    };

    // quarter-pipelined consume: load quarter q+1 before computing quarter q.
    // Same rotated chunk order as R10/R11 -> identical accumulation numerics.
    const int cq0 = 4*qrot;
    const int cq1 = 4*((qrot+1)&3);
    const int cq2 = 4*((qrot+2)&3);
    const int cq3 = 4*((qrot+3)&3);
    St SA0,SA1,SA2,SA3, SB0,SB1,SB2,SB3;
    waitq(cq0 >> 2);
    SA0=ldc(cq0+0); SA1=ldc(cq0+1); SA2=ldc(cq0+2); SA3=ldc(cq0+3);
    waitq(cq1 >> 2);
    SB0=ldc(cq1+0); SB1=ldc(cq1+1); SB2=ldc(cq1+2); SB3=ldc(cq1+3);
    cmp(SA0,cq0+0); cmp(SA1,cq0+1); cmp(SA2,cq0+2); cmp(SA3,cq0+3);
    waitq(cq2 >> 2);
    SA0=ldc(cq2+0); SA1=ldc(cq2+1); SA2=ldc(cq2+2); SA3=ldc(cq2+3);
    cmp(SB0,cq1+0); cmp(SB1,cq1+1); cmp(SB2,cq1+2); cmp(SB3,cq1+3);
    waitq(cq3 >> 2);
    SB0=ldc(cq3+0); SB1=ldc(cq3+1); SB2=ldc(cq3+2); SB3=ldc(cq3+3);
    cmp(SA0,cq2+0); cmp(SA1,cq2+1); cmp(SA2,cq2+2); cmp(SA3,cq2+3);
    cmp(SB0,cq3+0); cmp(SB1,cq3+1); cmp(SB2,cq3+2); cmp(SB3,cq3+3);

    // out(t-1) partial: thread tid covers k = tid, batch row b_out (all gates passed)
    const int oidx = sR2 + (tid>>3)*2048 + b_out*8 + (tid&7);
    float opart = join_h(h2h[oidx], h2l[oidx]) * wlin_s[tid];

    float* xw = &xch[wv][0];
    // ---- layer-2 cell (lane -> jj=quad, b=bcol after exchange) ----
    {
      f32x4 pre;
      #pragma unroll
      for (int i = 0; i < 4; ++i) pre[i] = fmaf(aB2[i], 1.0f/2048.0f, aA2[i]);
      *(f32x4*)&xw[lc*PADX + quad*4] = pre;          // [col][row], padded
      __threadfence_block();
      const float g0 = xw[lc*PADX + 0*4 + quad];
      const float g1 = xw[lc*PADX + 1*4 + quad];
      const float g2 = xw[lc*PADX + 2*4 + quad];
      const float g3 = xw[lc*PADX + 3*4 + quad];
      const float gi = fast_sigmoid(g0 + b2r[0]);
      const float gf = fast_sigmoid(g1 + b2r[1]);
      const float gg = fast_tanh   (g2 + b2r[2]);
      const float go = fast_sigmoid(g3 + b2r[3]);
      c2 = fmaf(gf, c2, gi*gg);
      const float hv = go * fast_tanh(c2);
      u16 hb; u8 lb; split_h(hv, hb, lb);
      st_wt_u16(&h2h[sW2 + hoff], hb);
      st_wt_u8 (&h2l[sW2 + hoff], lb);
    }
    // ---- layer-1 cell (for t+1) ----
    {
      f32x4 pre;
      #pragma unroll
      for (int i = 0; i < 4; ++i) pre[i] = fmaf(aB1[i], 1.0f/2048.0f, aA1[i]);
      __threadfence_block();                          // prior reads done before overwrite
      *(f32x4*)&xw[lc*PADX + quad*4] = pre;
      __threadfence_block();
      const float g0 = xw[lc*PADX + 0*4 + quad];
      const float g1 = xw[lc*PADX + 1*4 + quad];
      const float g2 = xw[lc*PADX + 2*4 + quad];
      const float g3 = xw[lc*PADX + 3*4 + quad];
      const int tx = (t+1 < TT) ? (t+1) : (TT-1);
      const float xv = xT[(size_t)tx*BB + bcol];
      const float gi = fast_sigmoid(g0 + fmaf(xv, wih1r[0], b1r[0]));
      const float gf = fast_sigmoid(g1 + fmaf(xv, wih1r[1], b1r[1]));
      const float gg = fast_tanh   (g2 + fmaf(xv, wih1r[2], b1r[2]));
      const float go = fast_sigmoid(g3 + fmaf(xv, wih1r[3], b1r[3]));
      c1 = fmaf(gf, c1, gi*gg);
      const float hv = go * fast_tanh(c1);
      u16 hb; u8 lb; split_h(hv, hb, lb);
      st_wt_u16(&h1h[sW1 + hoff], hb);
      st_wt_u8 (&h1l[sW1 + hoff], lb);
    }
    // ---- out(t-1) reduce (lands pre-syncthreads) ----
    #pragma unroll
    for (int off = 32; off > 0; off >>= 1) opart += __shfl_down(opart, off, 64);
    if (l == 0) outpart[t & 1][wv] = opart;

    // ---- arrival tail (OVERLAPPED): one drain barrier, then tid0 fires the
    // arrival (+inv on t%7==6) while tid64 writes out(t-1) and all other
    // waves proceed straight into the next phase's gates/loads. No second
    // __syncthreads: post-gate loads are always fresh (see header), and
    // run-ahead is bounded to <=1 phase by the gate structure.
    __syncthreads();                                   // drains WT stores; outpart ready
    if (tid == 0){
      __builtin_amdgcn_fence(__ATOMIC_RELEASE, "workgroup");   // ordering only, no wbl2
      __hip_atomic_fetch_add(&dbar[grp*16], 1u, __ATOMIC_RELAXED, __HIP_MEMORY_SCOPE_AGENT);
      if (t % 7 == 6){
        __builtin_amdgcn_fence(__ATOMIC_ACQUIRE, "agent");  // inv overlaps consumers' loads
      }
    } else if (tid == 64 && t > 0){                    // wave-1 lane0: out store, parallel to tid0
      float s = blin;
      #pragma unroll
      for (int q2i = 0; q2i < 8; ++q2i) s += outpart[t & 1][q2i];
      st_wt_f32(&out[(size_t)b_out*TT + (t-1)], s);
    }
    got = poll_mask(8u * (unsigned)(t+1));             // pre-poll next phase
  }

  // ---------------- tail: out(1023) (needs all phase-1023 arrivals) ----------------
  {
    const unsigned needT = 8u * (unsigned)TT;
    while (got != 0xFFFFu){
      __builtin_amdgcn_s_sleep(1);
      got |= poll_mask(needT);
    }
    asm volatile("" ::: "memory");

    const int oidx = ((TT-1)&(NSLOT-1))*SLOT + (tid>>3)*2048 + b_out*8 + (tid&7);
    float opart = join_h(h2h[oidx], h2l[oidx]) * wlin_s[tid];
    #pragma unroll
    for (int off = 32; off > 0; off >>= 1) opart += __shfl_down(opart, off, 64);
    if (l == 0) outpart[0][wv] = opart;
    __syncthreads();
    if (tid == 0){
      float s = blin;
      #pragma unroll
      for (int q2i = 0; q2i < 8; ++q2i) s += outpart[0][q2i];
      st_wt_f32(&out[(size_t)b_out*TT + (TT-1)], s);
    }
  }
}

extern "C" void kernel_launch(void* const* d_in, const int* in_sizes, int n_in,
                              void* d_out, int out_size, void* d_ws, size_t ws_size,
                              hipStream_t stream) {
  const float* x     = (const float*)d_in[0];
  const float* W_ih1 = (const float*)d_in[1];
  const float* W_hh1 = (const float*)d_in[2];
  const float* b1    = (const float*)d_in[3];
  const float* W_ih2 = (const float*)d_in[4];
  const float* W_hh2 = (const float*)d_in[5];
  const float* b2    = (const float*)d_in[6];
  const float* W_lin = (const float*)d_in[7];
  const float* b_lin = (const float*)d_in[8];
  float* out = (float*)d_out;
  char* wsb  = (char*)d_ws;

  // zero the barrier region (ws is re-poisoned to 0xAA before every launch)
  hipMemsetAsync(d_ws, 0, 16384, stream);

  hipLaunchKernelGGL(lstm_mfma, dim3(NWG), dim3(NTHR), 0, stream,
                     x, W_ih1, W_hh1, b1, W_ih2, W_hh2, b2, W_lin, b_lin, out, wsb);
}